// Round 1
// baseline (344.186 us; speedup 1.0000x reference)
//
#include <hip/hip_runtime.h>
#include <math.h>

// Problem constants (from reference): B=256, DIM=16, H_IN=H_OUT=32,
// IN_F=OUT_F=512. hyper_w is [B,512,512] fp32 (256 MB) — dominant traffic.
// w = exp(hw) on diagonal 32x32 blocks (rb==cb), hw on strictly-lower blocks
// (rb>cb), 0 on upper blocks. Only the lower-triangular prefix of each row is
// ever needed: row in block rb has (rb+1)*32 active columns (contiguous).
//
// Algebra: outputs[b,o] = (exp(sc)/sqrt(F2[b])) * (sum_i w[b,o,i]*x[b,i]) + hb[b,o]
//          out_log_det[b,d,o] = sc - 0.5*log(F2[b]) + logsumexp_i(hw_diag[b,d,o,i] + lgc[b,d,i])
// so one streaming pass computes raw matvec, raw lse and F2 simultaneously;
// a tiny finalize kernel applies the per-sample scalars in place.

#define OUT_OFF 131072   // outputs region size (256*512); lse region follows

__global__ __launch_bounds__(256) void mw_main(
    const float* __restrict__ hw,      // [B,512,512]
    const float* __restrict__ x,       // [B,512]
    const float* __restrict__ lgc,     // [B,16,32]
    float* __restrict__ out,           // [0..131071]=raw matvec, [131072..262143]=raw lse
    float* __restrict__ f2_partial)    // [B*16]
{
    const int blk = blockIdx.x;
    const int b  = blk >> 4;       // sample
    const int rb = blk & 15;       // row block (= d for the diagonal block)
    const int t  = threadIdx.x;
    const int r   = t >> 3;        // row within block, 0..31
    const int sub = t & 7;         // float4 slot within a 32-float chunk
    const int o = rb * 32 + r;     // global output row

    const float4* __restrict__ row4 = (const float4*)(hw + ((size_t)(b * 512 + o)) * 512);
    const float4* __restrict__ x4   = (const float4*)(x + (size_t)b * 512);

    float acc = 0.0f;   // sum_i w*x for this thread's columns
    float f2  = 0.0f;   // sum w^2

    // --- strictly-lower blocks: j in [0, rb), w = hw ---
    #pragma unroll 2
    for (int j = 0; j < rb; ++j) {
        float4 v  = row4[j * 8 + sub];
        float4 xv = x4[j * 8 + sub];
        acc += v.x * xv.x + v.y * xv.y + v.z * xv.z + v.w * xv.w;
        f2  += v.x * v.x + v.y * v.y + v.z * v.z + v.w * v.w;
    }

    // --- diagonal block: j == rb, w = exp(hw); also feeds the logsumexp ---
    float m, s;
    {
        float4 v  = row4[rb * 8 + sub];
        float4 xv = x4[rb * 8 + sub];
        float4 l4 = ((const float4*)(lgc + (size_t)b * 512 + rb * 32))[sub];
        float e0 = expf(v.x), e1 = expf(v.y), e2 = expf(v.z), e3 = expf(v.w);
        acc += e0 * xv.x + e1 * xv.y + e2 * xv.z + e3 * xv.w;
        f2  += e0 * e0 + e1 * e1 + e2 * e2 + e3 * e3;
        float a0 = v.x + l4.x, a1 = v.y + l4.y, a2 = v.z + l4.z, a3 = v.w + l4.w;
        m = fmaxf(fmaxf(a0, a1), fmaxf(a2, a3));
        s = expf(a0 - m) + expf(a1 - m) + expf(a2 - m) + expf(a3 - m);
    }

    // --- reduce matvec + (m,s) across the 8 lanes owning this row ---
    #pragma unroll
    for (int d = 1; d < 8; d <<= 1) {
        acc += __shfl_xor(acc, d, 64);
        float mo = __shfl_xor(m, d, 64);
        float so = __shfl_xor(s, d, 64);
        float mn = fmaxf(m, mo);
        s = s * expf(m - mn) + so * expf(mo - mn);
        m = mn;
    }
    if (sub == 0) {
        out[b * 512 + o]           = acc;           // raw matvec
        out[OUT_OFF + b * 512 + o] = m + logf(s);   // raw logsumexp
    }

    // --- block-wide F2 partial ---
    #pragma unroll
    for (int d = 1; d < 64; d <<= 1) f2 += __shfl_xor(f2, d, 64);
    __shared__ float sf[4];
    if ((t & 63) == 0) sf[t >> 6] = f2;
    __syncthreads();
    if (t == 0) f2_partial[b * 16 + rb] = sf[0] + sf[1] + sf[2] + sf[3];
}

__global__ __launch_bounds__(256) void mw_final(
    const float* __restrict__ f2_partial,  // [B*16]
    const float* __restrict__ hb,          // [B,512]
    const float* __restrict__ scale,       // [1]
    float* __restrict__ out)
{
    const int b = blockIdx.x;
    const int t = threadIdx.x;

    float f2 = 0.0f;
    #pragma unroll
    for (int k = 0; k < 16; ++k) f2 += f2_partial[b * 16 + k];

    const float sc     = scale[0];
    const float coef   = expf(sc) / sqrtf(f2);
    const float logoff = sc - 0.5f * logf(f2);

    #pragma unroll
    for (int k = 0; k < 2; ++k) {
        const int o  = t + k * 256;
        const int io = b * 512 + o;
        out[io]           = coef * out[io] + hb[io];
        out[OUT_OFF + io] += logoff;
    }
}

extern "C" void kernel_launch(void* const* d_in, const int* in_sizes, int n_in,
                              void* d_out, int out_size, void* d_ws, size_t ws_size,
                              hipStream_t stream) {
    const float* x     = (const float*)d_in[0];   // inputs         [256,512]
    const float* hw    = (const float*)d_in[1];   // hyper_w        [256,512,512]
    const float* hb    = (const float*)d_in[2];   // hyper_b        [256,512]
    const float* lgc   = (const float*)d_in[3];   // log_grad_cumul [256,16,32,1]
    const float* scale = (const float*)d_in[4];   // scale_factor   [1]
    float* out = (float*)d_out;
    float* f2p = (float*)d_ws;                    // 256*16 floats = 16 KB scratch

    mw_main<<<dim3(256 * 16), dim3(256), 0, stream>>>(hw, x, lgc, out, f2p);
    mw_final<<<dim3(256), dim3(256), 0, stream>>>(f2p, hb, scale, out);
}

// Round 3
// 326.610 us; speedup vs baseline: 1.0538x; 1.0538x over previous
//
#include <hip/hip_runtime.h>
#include <math.h>

// B=256, DIM=16, H=32, IN_F=OUT_F=512. hyper_w [B,512,512] fp32 dominant.
// Only the lower-block-triangular prefix of each row is live: row in block rb
// has (rb+1)*32 active columns. Single streaming pass computes raw matvec,
// raw logsumexp (diag block) and Frobenius partials; finalize applies the
// per-sample scalars (logsumexp shift-invariance + linear scaling).
//
// Balance: block handles row-block PAIR (pr, 15-pr) -> uniform 17
// chunk-iterations per thread. x/lgc staged in LDS (broadcast reads).

#define OUT_OFF 131072   // outputs region floats; lse region follows

typedef float f4 __attribute__((ext_vector_type(4)));

__global__ __launch_bounds__(256) void mw_main(
    const float* __restrict__ hw,      // [B,512,512]
    const float* __restrict__ x,       // [B,512]
    const float* __restrict__ lgc,     // [B,16,32]
    float* __restrict__ out,           // [0..131071]=raw matvec, [131072..]=raw lse
    float* __restrict__ f2_partial)    // [B*8]
{
    const int blk = blockIdx.x;
    const int b   = blk >> 3;
    const int pr  = blk & 7;
    const int rbA = pr;          // 0..7   (rbA lower chunks + diag)
    const int rbB = 15 - pr;     // 15..8  (rbB lower chunks + diag)
    const int t   = threadIdx.x;
    const int r   = t >> 3;      // row within block, 0..31
    const int sub = t & 7;       // float4 slot within 32-float chunk

    __shared__ f4 xs[128];   // sample's x: 512 floats
    __shared__ f4 ls[16];    // lgc chunks for rbA (0..7) and rbB (8..15)
    if (t < 128) xs[t] = ((const f4*)(x + (size_t)b * 512))[t];
    if (t >= 128 && t < 136) ls[t - 128] = ((const f4*)(lgc + (size_t)b * 512 + rbA * 32))[t - 128];
    if (t >= 136 && t < 144) ls[t - 128] = ((const f4*)(lgc + (size_t)b * 512 + rbB * 32))[t - 136];
    __syncthreads();

    const f4* __restrict__ rowA = (const f4*)(hw + ((size_t)(b * 512 + rbA * 32 + r)) * 512);
    const f4* __restrict__ rowB = (const f4*)(hw + ((size_t)(b * 512 + rbB * 32 + r)) * 512);

    float accA = 0.f, f2A = 0.f, accB = 0.f, f2B = 0.f;

    // --- fused lower-block sweep: j<rbA covers both streams, then B-only ---
    int j = 0;
    #pragma unroll 2
    for (; j < rbA; ++j) {
        f4 va = __builtin_nontemporal_load(rowA + j * 8 + sub);
        f4 vb = __builtin_nontemporal_load(rowB + j * 8 + sub);
        f4 xv = xs[j * 8 + sub];
        accA += va.x * xv.x + va.y * xv.y + va.z * xv.z + va.w * xv.w;
        f2A  += va.x * va.x + va.y * va.y + va.z * va.z + va.w * va.w;
        accB += vb.x * xv.x + vb.y * xv.y + vb.z * xv.z + vb.w * xv.w;
        f2B  += vb.x * vb.x + vb.y * vb.y + vb.z * vb.z + vb.w * vb.w;
    }
    #pragma unroll 4
    for (; j < rbB; ++j) {
        f4 vb = __builtin_nontemporal_load(rowB + j * 8 + sub);
        f4 xv = xs[j * 8 + sub];
        accB += vb.x * xv.x + vb.y * xv.y + vb.z * xv.z + vb.w * xv.w;
        f2B  += vb.x * vb.x + vb.y * vb.y + vb.z * vb.z + vb.w * vb.w;
    }

    // --- diagonal chunks (w = exp(hw)) + logsumexp inputs ---
    float mA, sA, mB, sB;
    {
        f4 va = __builtin_nontemporal_load(rowA + rbA * 8 + sub);
        f4 vb = __builtin_nontemporal_load(rowB + rbB * 8 + sub);
        f4 xa = xs[rbA * 8 + sub];
        f4 xb = xs[rbB * 8 + sub];
        f4 la = ls[sub];
        f4 lb = ls[8 + sub];
        float e0 = expf(va.x), e1 = expf(va.y), e2 = expf(va.z), e3 = expf(va.w);
        accA += e0 * xa.x + e1 * xa.y + e2 * xa.z + e3 * xa.w;
        f2A  += e0 * e0 + e1 * e1 + e2 * e2 + e3 * e3;
        float a0 = va.x + la.x, a1 = va.y + la.y, a2 = va.z + la.z, a3 = va.w + la.w;
        mA = fmaxf(fmaxf(a0, a1), fmaxf(a2, a3));
        sA = expf(a0 - mA) + expf(a1 - mA) + expf(a2 - mA) + expf(a3 - mA);
        float g0 = expf(vb.x), g1 = expf(vb.y), g2 = expf(vb.z), g3 = expf(vb.w);
        accB += g0 * xb.x + g1 * xb.y + g2 * xb.z + g3 * xb.w;
        f2B  += g0 * g0 + g1 * g1 + g2 * g2 + g3 * g3;
        float b0 = vb.x + lb.x, b1 = vb.y + lb.y, b2 = vb.z + lb.z, b3 = vb.w + lb.w;
        mB = fmaxf(fmaxf(b0, b1), fmaxf(b2, b3));
        sB = expf(b0 - mB) + expf(b1 - mB) + expf(b2 - mB) + expf(b3 - mB);
    }

    // --- reduce across the 8 lanes owning each row ---
    #pragma unroll
    for (int d = 1; d < 8; d <<= 1) {
        accA += __shfl_xor(accA, d, 64);
        accB += __shfl_xor(accB, d, 64);
        float mo, so, mn;
        mo = __shfl_xor(mA, d, 64); so = __shfl_xor(sA, d, 64);
        mn = fmaxf(mA, mo); sA = sA * expf(mA - mn) + so * expf(mo - mn); mA = mn;
        mo = __shfl_xor(mB, d, 64); so = __shfl_xor(sB, d, 64);
        mn = fmaxf(mB, mo); sB = sB * expf(mB - mn) + so * expf(mo - mn); mB = mn;
    }
    if (sub == 0) {
        const int oA = rbA * 32 + r, oB = rbB * 32 + r;
        out[b * 512 + oA]           = accA;
        out[OUT_OFF + b * 512 + oA] = mA + logf(sA);
        out[b * 512 + oB]           = accB;
        out[OUT_OFF + b * 512 + oB] = mB + logf(sB);
    }

    // --- block-wide F2 partial ---
    float f2 = f2A + f2B;
    #pragma unroll
    for (int d = 1; d < 64; d <<= 1) f2 += __shfl_xor(f2, d, 64);
    __shared__ float sf[4];
    if ((t & 63) == 0) sf[t >> 6] = f2;
    __syncthreads();
    if (t == 0) f2_partial[b * 8 + pr] = sf[0] + sf[1] + sf[2] + sf[3];
}

__global__ __launch_bounds__(256) void mw_final(
    const float* __restrict__ f2_partial,  // [B*8]
    const float* __restrict__ hb,          // [B,512]
    const float* __restrict__ scale,       // [1]
    float* __restrict__ out)
{
    const int b = blockIdx.x;
    const int t = threadIdx.x;

    float f2 = 0.0f;
    #pragma unroll
    for (int k = 0; k < 8; ++k) f2 += f2_partial[b * 8 + k];

    const float sc     = scale[0];
    const float coef   = expf(sc) / sqrtf(f2);
    const float logoff = sc - 0.5f * logf(f2);

    #pragma unroll
    for (int k = 0; k < 2; ++k) {
        const int o  = t + k * 256;
        const int io = b * 512 + o;
        out[io]           = coef * out[io] + hb[io];
        out[OUT_OFF + io] += logoff;
    }
}

extern "C" void kernel_launch(void* const* d_in, const int* in_sizes, int n_in,
                              void* d_out, int out_size, void* d_ws, size_t ws_size,
                              hipStream_t stream) {
    const float* x     = (const float*)d_in[0];   // inputs         [256,512]
    const float* hw    = (const float*)d_in[1];   // hyper_w        [256,512,512]
    const float* hb    = (const float*)d_in[2];   // hyper_b        [256,512]
    const float* lgc   = (const float*)d_in[3];   // log_grad_cumul [256,16,32,1]
    const float* scale = (const float*)d_in[4];   // scale_factor   [1]
    float* out = (float*)d_out;
    float* f2p = (float*)d_ws;                    // 256*8 floats = 8 KB scratch

    mw_main<<<dim3(256 * 8), dim3(256), 0, stream>>>(hw, x, lgc, out, f2p);
    mw_final<<<dim3(256), dim3(256), 0, stream>>>(f2p, hb, scale, out);
}

// Round 4
// 325.947 us; speedup vs baseline: 1.0560x; 1.0020x over previous
//
#include <hip/hip_runtime.h>
#include <math.h>

// B=256, DIM=16, H=32, IN_F=OUT_F=512. hyper_w [B,512,512] fp32 dominant
// (256 MB, but only the lower-block-triangular 53% = 142.6 MB is live).
// One streaming pass computes raw matvec, raw diag-block logsumexp, and
// Frobenius partials; tiny finalize applies per-sample scalars (logsumexp
// shift-invariance + linearity). Block = row-block pair (pr, 15-pr) ->
// uniform 17 chunk-iters. pr is block-uniform with 8 values: dispatch to
// template instantiations so all trip counts are compile-time (full unroll,
// maximal load hoisting / ILP).

#define OUT_OFF 131072   // outputs region floats; lse region follows

typedef float f4 __attribute__((ext_vector_type(4)));

template<int RBA>
__device__ __forceinline__ void mw_body(
    const float* __restrict__ hw,
    const f4* __restrict__ xs,
    const f4* __restrict__ ls,
    float* __restrict__ sf,
    int b, int t,
    float* __restrict__ out,
    float* __restrict__ f2_partial)
{
    constexpr int RBB = 15 - RBA;
    const int r   = t >> 3;      // row within block, 0..31
    const int sub = t & 7;       // f4 slot within 32-float chunk

    const f4* __restrict__ rowA = (const f4*)(hw + ((size_t)(b * 512 + RBA * 32 + r)) * 512);
    const f4* __restrict__ rowB = (const f4*)(hw + ((size_t)(b * 512 + RBB * 32 + r)) * 512);

    float accA = 0.f, f2A = 0.f, accB = 0.f, f2B = 0.f;

    // --- strictly-lower blocks, dual stream for j < RBA ---
    #pragma unroll
    for (int j = 0; j < RBA; ++j) {
        f4 va = __builtin_nontemporal_load(rowA + j * 8 + sub);
        f4 vb = __builtin_nontemporal_load(rowB + j * 8 + sub);
        f4 xv = xs[j * 8 + sub];
        accA += va.x * xv.x + va.y * xv.y + va.z * xv.z + va.w * xv.w;
        f2A  += va.x * va.x + va.y * va.y + va.z * va.z + va.w * va.w;
        accB += vb.x * xv.x + vb.y * xv.y + vb.z * xv.z + vb.w * xv.w;
        f2B  += vb.x * vb.x + vb.y * vb.y + vb.z * vb.z + vb.w * vb.w;
    }
    // --- B-only region ---
    #pragma unroll
    for (int j = RBA; j < RBB; ++j) {
        f4 vb = __builtin_nontemporal_load(rowB + j * 8 + sub);
        f4 xv = xs[j * 8 + sub];
        accB += vb.x * xv.x + vb.y * xv.y + vb.z * xv.z + vb.w * xv.w;
        f2B  += vb.x * vb.x + vb.y * vb.y + vb.z * vb.z + vb.w * vb.w;
    }

    // --- diagonal chunks (w = exp(hw)) + logsumexp inputs ---
    float mA, sA, mB, sB;
    {
        f4 va = __builtin_nontemporal_load(rowA + RBA * 8 + sub);
        f4 vb = __builtin_nontemporal_load(rowB + RBB * 8 + sub);
        f4 xa = xs[RBA * 8 + sub];
        f4 xb = xs[RBB * 8 + sub];
        f4 la = ls[sub];
        f4 lb = ls[8 + sub];
        float e0 = expf(va.x), e1 = expf(va.y), e2 = expf(va.z), e3 = expf(va.w);
        accA += e0 * xa.x + e1 * xa.y + e2 * xa.z + e3 * xa.w;
        f2A  += e0 * e0 + e1 * e1 + e2 * e2 + e3 * e3;
        float a0 = va.x + la.x, a1 = va.y + la.y, a2 = va.z + la.z, a3 = va.w + la.w;
        mA = fmaxf(fmaxf(a0, a1), fmaxf(a2, a3));
        sA = expf(a0 - mA) + expf(a1 - mA) + expf(a2 - mA) + expf(a3 - mA);
        float g0 = expf(vb.x), g1 = expf(vb.y), g2 = expf(vb.z), g3 = expf(vb.w);
        accB += g0 * xb.x + g1 * xb.y + g2 * xb.z + g3 * xb.w;
        f2B  += g0 * g0 + g1 * g1 + g2 * g2 + g3 * g3;
        float b0 = vb.x + lb.x, b1 = vb.y + lb.y, b2 = vb.z + lb.z, b3 = vb.w + lb.w;
        mB = fmaxf(fmaxf(b0, b1), fmaxf(b2, b3));
        sB = expf(b0 - mB) + expf(b1 - mB) + expf(b2 - mB) + expf(b3 - mB);
    }

    // --- reduce across the 8 lanes owning each row ---
    #pragma unroll
    for (int d = 1; d < 8; d <<= 1) {
        accA += __shfl_xor(accA, d, 64);
        accB += __shfl_xor(accB, d, 64);
        float mo, so, mn;
        mo = __shfl_xor(mA, d, 64); so = __shfl_xor(sA, d, 64);
        mn = fmaxf(mA, mo); sA = sA * expf(mA - mn) + so * expf(mo - mn); mA = mn;
        mo = __shfl_xor(mB, d, 64); so = __shfl_xor(sB, d, 64);
        mn = fmaxf(mB, mo); sB = sB * expf(mB - mn) + so * expf(mo - mn); mB = mn;
    }
    if (sub == 0) {
        const int oA = RBA * 32 + r, oB = RBB * 32 + r;
        out[b * 512 + oA]           = accA;
        out[OUT_OFF + b * 512 + oA] = mA + logf(sA);
        out[b * 512 + oB]           = accB;
        out[OUT_OFF + b * 512 + oB] = mB + logf(sB);
    }

    // --- block-wide F2 partial ---
    float f2 = f2A + f2B;
    #pragma unroll
    for (int d = 1; d < 64; d <<= 1) f2 += __shfl_xor(f2, d, 64);
    if ((t & 63) == 0) sf[t >> 6] = f2;
    __syncthreads();
    if (t == 0) f2_partial[b * 8 + RBA] = sf[0] + sf[1] + sf[2] + sf[3];
}

__global__ __launch_bounds__(256) void mw_main(
    const float* __restrict__ hw,      // [B,512,512]
    const float* __restrict__ x,       // [B,512]
    const float* __restrict__ lgc,     // [B,16,32]
    float* __restrict__ out,           // [0..131071]=raw matvec, [131072..]=raw lse
    float* __restrict__ f2_partial)    // [B*8]
{
    const int blk = blockIdx.x;
    const int b   = blk >> 3;
    const int pr  = blk & 7;
    const int rbA = pr, rbB = 15 - pr;
    const int t   = threadIdx.x;

    __shared__ f4 xs[128];   // sample's x: 512 floats
    __shared__ f4 ls[16];    // lgc chunks for rbA (0..7) and rbB (8..15)
    __shared__ float sf[4];
    if (t < 128) xs[t] = ((const f4*)(x + (size_t)b * 512))[t];
    if (t >= 128 && t < 136) ls[t - 128] = ((const f4*)(lgc + (size_t)b * 512 + rbA * 32))[t - 128];
    if (t >= 136 && t < 144) ls[t - 128] = ((const f4*)(lgc + (size_t)b * 512 + rbB * 32))[t - 136];
    __syncthreads();

    switch (pr) {
        case 0: mw_body<0>(hw, xs, ls, sf, b, t, out, f2_partial); break;
        case 1: mw_body<1>(hw, xs, ls, sf, b, t, out, f2_partial); break;
        case 2: mw_body<2>(hw, xs, ls, sf, b, t, out, f2_partial); break;
        case 3: mw_body<3>(hw, xs, ls, sf, b, t, out, f2_partial); break;
        case 4: mw_body<4>(hw, xs, ls, sf, b, t, out, f2_partial); break;
        case 5: mw_body<5>(hw, xs, ls, sf, b, t, out, f2_partial); break;
        case 6: mw_body<6>(hw, xs, ls, sf, b, t, out, f2_partial); break;
        case 7: mw_body<7>(hw, xs, ls, sf, b, t, out, f2_partial); break;
    }
}

__global__ __launch_bounds__(256) void mw_final(
    const float* __restrict__ f2_partial,  // [B*8]
    const float* __restrict__ hb,          // [B,512]
    const float* __restrict__ scale,       // [1]
    float* __restrict__ out)
{
    const int b = blockIdx.x;
    const int t = threadIdx.x;

    float f2 = 0.0f;
    #pragma unroll
    for (int k = 0; k < 8; ++k) f2 += f2_partial[b * 8 + k];

    const float sc     = scale[0];
    const float coef   = expf(sc) / sqrtf(f2);
    const float logoff = sc - 0.5f * logf(f2);

    #pragma unroll
    for (int k = 0; k < 2; ++k) {
        const int o  = t + k * 256;
        const int io = b * 512 + o;
        out[io]           = coef * out[io] + hb[io];
        out[OUT_OFF + io] += logoff;
    }
}

extern "C" void kernel_launch(void* const* d_in, const int* in_sizes, int n_in,
                              void* d_out, int out_size, void* d_ws, size_t ws_size,
                              hipStream_t stream) {
    const float* x     = (const float*)d_in[0];   // inputs         [256,512]
    const float* hw    = (const float*)d_in[1];   // hyper_w        [256,512,512]
    const float* hb    = (const float*)d_in[2];   // hyper_b        [256,512]
    const float* lgc   = (const float*)d_in[3];   // log_grad_cumul [256,16,32,1]
    const float* scale = (const float*)d_in[4];   // scale_factor   [1]
    float* out = (float*)d_out;
    float* f2p = (float*)d_ws;                    // 256*8 floats = 8 KB scratch

    mw_main<<<dim3(256 * 8), dim3(256), 0, stream>>>(hw, x, lgc, out, f2p);
    mw_final<<<dim3(256), dim3(256), 0, stream>>>(f2p, hb, scale, out);
}